// Round 8
// baseline (203.494 us; speedup 1.0000x reference)
//
#include <hip/hip_runtime.h>

// LSTM B=8192, T=512, I=1, H=32; out[b] = h_T . W_lin + b_lin.  All I/O f32.
//
// R21: R20 (R13 + setprio) with the prio-1 window EXTENDED to the whole
// serial chain: ds_read(bfrag) -> MFMAs -> acts -> ds_write. Only C-init
// and the barrier wait run at prio 0.
//
// R20 post-mortem (179 -> 150.7 us rocprof, -16%): per-wave issue was
// unchanged (busy/SIMD 498 = 2 x [12 trans x16 + ~55 VALU]); the gain was
// pure arbitration — the prio-0 co-block wave's slack work no longer
// steals issue slots from the prio-1 wave's act chain. Remaining wall
// 706 = trans floor 384 + VALU ~114 + ~140 simultaneous-stall. The chain's
// FRONT half (ds_read ~130 + MFMA ~30) still ran at prio 0 in R20; this
// round prioritizes it too. Predict 139-147 rocprof; if >=148, remaining
// idle is aligned-stall, structure is at its floor -> terminal.
//
// Structure-search verdict (R15-R19, all measured): R13's 4-wave/16-batch
// exchange structure is the family optimum (801 cyc/step pre-setprio).
//   R15 1-wave/SIMD dual-group: 1125 (wall=P+I; co-wave was free cover)
//   R16/R17/R18 lane-local 1-wave: ~1460 (48 trans/step on ONE SIMD;
//     trans op ~16 cyc issue; staging/ILP/regs irrelevant)
//   R19 8-batch 2-wave blocks: 1023 (per-wave I up, no added cover)
//
// MFMA formulation, 4 waves per 16-batch group (512 blocks x 256 threads),
// custom tiles (zero MFMA duplication), 2 hiddens/lane, fused activations
// with PAIRED rcp. Wave wv owns hiddens [8wv, 8wv+8). Lane (quad,col) owns
// j0 = 8wv+2quad+0 and j1 = j0+1 of batch col. Custom A-tile tau: row
// m = 4a+r holds W_hh gate-row [type r][hidden 8wv+2a+tau], so acc[tau]
// slots 0..3 = {i,f,g,o} of hidden j0+tau. 2 MFMAs/wave-step. 2048 waves.
//
// Activations (12 trans/lane-step = 10 exp2 + 2 paired rcp — algebraic
// floor): e* = 2^(-z*'), a* = 1+e*; D = aF*aI*aG;
// paired: r = rcp(D0*D1); c' = (c*aI*aG + (1-eG)*aF)/D;
// eC = 2^(-2*L2E*c'); H = aO*(1+eC) paired-rcp; h = (1-eC)/H.
// Pre-acts pre-scaled by L2E (2*L2E for g).
//
// Ledger (rocprof us / cyc-per-step): R13 179/801 -> R15 240 F -> R16-18
// ~310 F -> R19 218 F -> R20 150.7/706 (setprio acts) -> this.
// NOTE: packed f32x2 (v_pk_*) acts failed post-timing determinism in R12 -
// do not reintroduce.

#define L2E 1.4426950408889634f

typedef _Float16 f16x8 __attribute__((ext_vector_type(8)));
typedef float    f32x4 __attribute__((ext_vector_type(4)));

__global__ __launch_bounds__(256, 4) void lstm_ct4r(
    const float* __restrict__ x,      // [B*512]
    const float* __restrict__ W_ih,   // [128]
    const float* __restrict__ W_hh,   // [128*32]
    const float* __restrict__ b_ih,   // [128]
    const float* __restrict__ b_hh,   // [128]
    const float* __restrict__ W_lin,  // [32]
    const float* __restrict__ b_lin,  // [1]
    float* __restrict__ out)          // [B]
{
    __shared__ float xs[512 * 17];                        // x transposed [t][b], stride 17
    __shared__ __align__(16) unsigned int hb[2][16 * 20]; // h half2 buffers, col-stride 20 uints
    __shared__ float ps[64];                              // epilogue partials

    const int tid  = threadIdx.x;
    const int wv   = tid >> 6;         // 0..3: owns hiddens [8wv, 8wv+8)
    const int lane = tid & 63;
    const int col  = lane & 15;        // batch within group
    const int quad = lane >> 4;        // 0..3
    const int base = blockIdx.x * 16;  // global batch base

    // ---- stage x[base..base+15][0..511] into LDS transposed ----
    {
        const float4* xg = (const float4*)(x + (size_t)base * 512);
        #pragma unroll
        for (int it = 0; it < 8; ++it) {
            int idx = it * 256 + tid;          // 0..2047 float4s
            float4 v = xg[idx];
            int b  = idx >> 7;                 // batch 0..15
            int t0 = (idx & 127) * 4;
            xs[(t0 + 0) * 17 + b] = v.x;
            xs[(t0 + 1) * 17 + b] = v.y;
            xs[(t0 + 2) * 17 + b] = v.z;
            xs[(t0 + 3) * 17 + b] = v.w;
        }
    }

    // ---- custom A-tiles: tile tau row m=4a+rt -> W_hh[32*rt + 8wv+2a+tau] ----
    f16x8 wA[2];
    #pragma unroll
    for (int tau = 0; tau < 2; ++tau) {
        const int rt = col & 3;                           // gate type of row col
        const float s = (rt == 2) ? (2.0f * L2E) : L2E;
        const int grow = 32 * rt + 8 * wv + 2 * (col >> 2) + tau;
        #pragma unroll
        for (int j = 0; j < 8; ++j)
            wA[tau][j] = (_Float16)(W_hh[grow * 32 + quad * 8 + j] * s);
    }
    // C-init constants: acc[tau] slot r = gate type r of hidden j0+tau
    const int j0 = 8 * wv + 2 * quad;                     // first owned hidden
    float wih[2][4], bia[2][4];
    #pragma unroll
    for (int tau = 0; tau < 2; ++tau)
        #pragma unroll
        for (int r = 0; r < 4; ++r) {
            const float s = (r == 2) ? (2.0f * L2E) : L2E;
            const int g = 32 * r + j0 + tau;
            wih[tau][r] = W_ih[g] * s;
            bia[tau][r] = (b_ih[g] + b_hh[g]) * s;
        }
    const float wl0 = W_lin[j0], wl1 = W_lin[j0 + 1];

    __syncthreads();

    float c0 = 0.0f, c1 = 0.0f, h0 = 0.0f, h1 = 0.0f;
    f16x8 bfrag = {};                  // h = 0
    f32x4 cq[2];
    {
        float xt = xs[col];            // t = 0
        #pragma unroll
        for (int tau = 0; tau < 2; ++tau)
            #pragma unroll
            for (int r = 0; r < 4; ++r)
                cq[tau][r] = fmaf(xt, wih[tau][r], bia[tau][r]);
    }

    const int wr = col * 20 + 4 * wv + quad;   // h-pair write index (= j0/2 slot)

    // enter the loop with the chain prioritized (bfrag already in regs for t=0)
    __builtin_amdgcn_s_setprio(1);

    #pragma unroll 4
    for (int t = 0; t < 512; ++t) {
        unsigned int* buf = hb[t & 1];

        f32x4 a0 = __builtin_amdgcn_mfma_f32_16x16x32_f16(wA[0], bfrag, cq[0], 0, 0, 0);
        f32x4 a1 = __builtin_amdgcn_mfma_f32_16x16x32_f16(wA[1], bfrag, cq[1], 0, 0, 0);

        float xt1 = xs[((t + 1) & 511) * 17 + col];       // prefetch next x

        // fused activations, hidden j0 (a0) and j0+1 (a1); rcps PAIRED
        float ei0 = __builtin_amdgcn_exp2f(-a0[0]);
        float ef0 = __builtin_amdgcn_exp2f(-a0[1]);
        float eg0 = __builtin_amdgcn_exp2f(-a0[2]);
        float eo0 = __builtin_amdgcn_exp2f(-a0[3]);
        float ei1 = __builtin_amdgcn_exp2f(-a1[0]);
        float ef1 = __builtin_amdgcn_exp2f(-a1[1]);
        float eg1 = __builtin_amdgcn_exp2f(-a1[2]);
        float eo1 = __builtin_amdgcn_exp2f(-a1[3]);
        float aI0 = 1.0f + ei0, aF0 = 1.0f + ef0, aG0 = 1.0f + eg0, aO0 = 1.0f + eo0;
        float aI1 = 1.0f + ei1, aF1 = 1.0f + ef1, aG1 = 1.0f + eg1, aO1 = 1.0f + eo1;
        float tIG0 = aI0 * aG0, tIG1 = aI1 * aG1;
        float num0 = fmaf(c0, tIG0, (1.0f - eg0) * aF0);
        float num1 = fmaf(c1, tIG1, (1.0f - eg1) * aF1);
        float D0 = aF0 * tIG0, D1 = aF1 * tIG1;
        float rD = __builtin_amdgcn_rcpf(D0 * D1);        // paired rcp #1
        c0 = num0 * (rD * D1);
        c1 = num1 * (rD * D0);
        float ec0 = __builtin_amdgcn_exp2f(c0 * (-2.0f * L2E));
        float ec1 = __builtin_amdgcn_exp2f(c1 * (-2.0f * L2E));
        float H0 = aO0 * (1.0f + ec0), H1 = aO1 * (1.0f + ec1);
        float rH = __builtin_amdgcn_rcpf(H0 * H1);        // paired rcp #2
        h0 = (1.0f - ec0) * (rH * H1);
        h1 = (1.0f - ec1) * (rH * H0);

        // adjacent hiddens -> one b32 write of the packed pair
        buf[wr] = __builtin_bit_cast(unsigned int, __builtin_amdgcn_cvt_pkrtz(h0, h1));

        // slack work at prio 0: C-init + barrier wait
        __builtin_amdgcn_s_setprio(0);

        #pragma unroll
        for (int tau = 0; tau < 2; ++tau)
            #pragma unroll
            for (int r = 0; r < 4; ++r)
                cq[tau][r] = fmaf(xt1, wih[tau][r], bia[tau][r]);

        __syncthreads();

        // chain resumes: prioritize the exchange read feeding next MFMA
        __builtin_amdgcn_s_setprio(1);
        // B-frag: pairs quad*4..+3 of batch col = k quad*8..quad*8+7
        uint4 bv = *(const uint4*)&buf[col * 20 + quad * 4];
        bfrag = __builtin_bit_cast(f16x8, bv);
    }

    __builtin_amdgcn_s_setprio(0);

    // ---- epilogue: out[b] = sum_j h_j * W_lin[j] + b_lin ----
    float v = fmaf(h0, wl0, h1 * wl1);
    v += __shfl_xor(v, 16);            // combine quads
    v += __shfl_xor(v, 32);
    if (lane < 16) ps[wv * 16 + col] = v;
    __syncthreads();
    if (tid < 16)
        out[base + tid] = b_lin[0] + ps[tid] + ps[16 + tid] + ps[32 + tid] + ps[48 + tid];
}

extern "C" void kernel_launch(void* const* d_in, const int* in_sizes, int n_in,
                              void* d_out, int out_size, void* d_ws, size_t ws_size,
                              hipStream_t stream) {
    const float* x     = (const float*)d_in[0];
    const float* W_ih  = (const float*)d_in[1];
    const float* W_hh  = (const float*)d_in[2];
    const float* b_ih  = (const float*)d_in[3];
    const float* b_hh  = (const float*)d_in[4];
    const float* W_lin = (const float*)d_in[5];
    const float* b_lin = (const float*)d_in[6];
    float* out = (float*)d_out;

    const int B = in_sizes[0] / 512;   // 8192
    dim3 grid(B / 16), block(256);
    lstm_ct4r<<<grid, block, 0, stream>>>(x, W_ih, W_hh, b_ih, b_hh, W_lin, b_lin, out);
}

// Round 9
// 194.525 us; speedup vs baseline: 1.0461x; 1.0461x over previous
//
#include <hip/hip_runtime.h>

// LSTM B=8192, T=512, I=1, H=32; out[b] = h_T . W_lin + b_lin.  All I/O f32.
//
// R22 == R20 (TERMINAL): R13 4-wave custom-tile structure + s_setprio(1)
// around ONLY the fused activation chain. Session-best: 150.7us rocprof /
// 195.8us harness (baseline R13: 179/217.9).
//
// Why terminal — every axis closed by measurement:
//  STRUCTURE (R15-R19): 4-wave/16-batch exchange is the family optimum.
//    R15 1-wave/SIMD dual-group 1125 cyc/step (wall=P+I; co-wave was free
//    bubble cover); R16/17/18 lane-local ~1460 (48 trans/step on ONE SIMD;
//    trans ~16cyc/wave-op issue; ILP/regs/staging all irrelevant);
//    R19 8-batch 2-wave 1023 (per-wave issue up, no added cover).
//  ALGEBRA: 10 exp2 + 2 paired rcp per lane-step = 5 exp2 + 1 rcp per
//    hidden-step = transcendental floor for 3 sigmoid + 2 tanh.
//  SCHEDULE (R20/R21): narrow prio-1 window on the act chain: -16%
//    (arbitration: co-wave's slack work no longer steals issue slots).
//    Extending the window to ds_read+MFMA (R21): +1.7% REGRESSION — both
//    waves then sit at prio 1, discrimination lost, C-init starved.
//    Remaining wall 706 = trans floor 384 + ~180 VALU/MFMA + ~140 aligned
//    stall (both waves stall together; not arbitrable).
//  Occupancy is grid-capped (512 groups = 2 blocks/CU); all restructures
//  that raise it were measured worse.
//
// MFMA formulation, 4 waves per 16-batch group (512 blocks x 256 threads),
// custom tiles (zero MFMA duplication), 2 hiddens/lane, fused activations
// with PAIRED rcp. Wave wv owns hiddens [8wv, 8wv+8). Lane (quad,col) owns
// j0 = 8wv+2quad+0 and j1 = j0+1 of batch col. Custom A-tile tau: row
// m = 4a+r holds W_hh gate-row [type r][hidden 8wv+2a+tau], so acc[tau]
// slots 0..3 = {i,f,g,o} of hidden j0+tau. 2 MFMAs/wave-step. 2048 waves.
//
// Activations: e* = 2^(-z*'), a* = 1+e*; D = aF*aI*aG;
// paired: r = rcp(D0*D1); c' = (c*aI*aG + (1-eG)*aF)/D;
// eC = 2^(-2*L2E*c'); H = aO*(1+eC) paired-rcp; h = (1-eC)/H.
// Pre-acts pre-scaled by L2E (2*L2E for g).
//
// Ledger (rocprof us): R13 179 -> R15 240 F -> R16-18 ~310 F -> R19 218 F
// -> R20 150.7 (setprio acts, THIS) -> R21 153.2 F (wide prio window).
// NOTE: packed f32x2 (v_pk_*) acts failed post-timing determinism in R12 -
// do not reintroduce.

#define L2E 1.4426950408889634f

typedef _Float16 f16x8 __attribute__((ext_vector_type(8)));
typedef float    f32x4 __attribute__((ext_vector_type(4)));

__global__ __launch_bounds__(256, 4) void lstm_ct4r(
    const float* __restrict__ x,      // [B*512]
    const float* __restrict__ W_ih,   // [128]
    const float* __restrict__ W_hh,   // [128*32]
    const float* __restrict__ b_ih,   // [128]
    const float* __restrict__ b_hh,   // [128]
    const float* __restrict__ W_lin,  // [32]
    const float* __restrict__ b_lin,  // [1]
    float* __restrict__ out)          // [B]
{
    __shared__ float xs[512 * 17];                        // x transposed [t][b], stride 17
    __shared__ __align__(16) unsigned int hb[2][16 * 20]; // h half2 buffers, col-stride 20 uints
    __shared__ float ps[64];                              // epilogue partials

    const int tid  = threadIdx.x;
    const int wv   = tid >> 6;         // 0..3: owns hiddens [8wv, 8wv+8)
    const int lane = tid & 63;
    const int col  = lane & 15;        // batch within group
    const int quad = lane >> 4;        // 0..3
    const int base = blockIdx.x * 16;  // global batch base

    // ---- stage x[base..base+15][0..511] into LDS transposed ----
    {
        const float4* xg = (const float4*)(x + (size_t)base * 512);
        #pragma unroll
        for (int it = 0; it < 8; ++it) {
            int idx = it * 256 + tid;          // 0..2047 float4s
            float4 v = xg[idx];
            int b  = idx >> 7;                 // batch 0..15
            int t0 = (idx & 127) * 4;
            xs[(t0 + 0) * 17 + b] = v.x;
            xs[(t0 + 1) * 17 + b] = v.y;
            xs[(t0 + 2) * 17 + b] = v.z;
            xs[(t0 + 3) * 17 + b] = v.w;
        }
    }

    // ---- custom A-tiles: tile tau row m=4a+rt -> W_hh[32*rt + 8wv+2a+tau] ----
    f16x8 wA[2];
    #pragma unroll
    for (int tau = 0; tau < 2; ++tau) {
        const int rt = col & 3;                           // gate type of row col
        const float s = (rt == 2) ? (2.0f * L2E) : L2E;
        const int grow = 32 * rt + 8 * wv + 2 * (col >> 2) + tau;
        #pragma unroll
        for (int j = 0; j < 8; ++j)
            wA[tau][j] = (_Float16)(W_hh[grow * 32 + quad * 8 + j] * s);
    }
    // C-init constants: acc[tau] slot r = gate type r of hidden j0+tau
    const int j0 = 8 * wv + 2 * quad;                     // first owned hidden
    float wih[2][4], bia[2][4];
    #pragma unroll
    for (int tau = 0; tau < 2; ++tau)
        #pragma unroll
        for (int r = 0; r < 4; ++r) {
            const float s = (r == 2) ? (2.0f * L2E) : L2E;
            const int g = 32 * r + j0 + tau;
            wih[tau][r] = W_ih[g] * s;
            bia[tau][r] = (b_ih[g] + b_hh[g]) * s;
        }
    const float wl0 = W_lin[j0], wl1 = W_lin[j0 + 1];

    __syncthreads();

    float c0 = 0.0f, c1 = 0.0f, h0 = 0.0f, h1 = 0.0f;
    f16x8 bfrag = {};                  // h = 0
    f32x4 cq[2];
    {
        float xt = xs[col];            // t = 0
        #pragma unroll
        for (int tau = 0; tau < 2; ++tau)
            #pragma unroll
            for (int r = 0; r < 4; ++r)
                cq[tau][r] = fmaf(xt, wih[tau][r], bia[tau][r]);
    }

    const int wr = col * 20 + 4 * wv + quad;   // h-pair write index (= j0/2 slot)

    #pragma unroll 4
    for (int t = 0; t < 512; ++t) {
        unsigned int* buf = hb[t & 1];

        f32x4 a0 = __builtin_amdgcn_mfma_f32_16x16x32_f16(wA[0], bfrag, cq[0], 0, 0, 0);
        f32x4 a1 = __builtin_amdgcn_mfma_f32_16x16x32_f16(wA[1], bfrag, cq[1], 0, 0, 0);

        float xt1 = xs[((t + 1) & 511) * 17 + col];       // prefetch next x

        // serial critical path: prioritize this wave over the co-block's
        // slack-phase work (narrow window — R21 showed wider regresses)
        __builtin_amdgcn_s_setprio(1);

        // fused activations, hidden j0 (a0) and j0+1 (a1); rcps PAIRED
        float ei0 = __builtin_amdgcn_exp2f(-a0[0]);
        float ef0 = __builtin_amdgcn_exp2f(-a0[1]);
        float eg0 = __builtin_amdgcn_exp2f(-a0[2]);
        float eo0 = __builtin_amdgcn_exp2f(-a0[3]);
        float ei1 = __builtin_amdgcn_exp2f(-a1[0]);
        float ef1 = __builtin_amdgcn_exp2f(-a1[1]);
        float eg1 = __builtin_amdgcn_exp2f(-a1[2]);
        float eo1 = __builtin_amdgcn_exp2f(-a1[3]);
        float aI0 = 1.0f + ei0, aF0 = 1.0f + ef0, aG0 = 1.0f + eg0, aO0 = 1.0f + eo0;
        float aI1 = 1.0f + ei1, aF1 = 1.0f + ef1, aG1 = 1.0f + eg1, aO1 = 1.0f + eo1;
        float tIG0 = aI0 * aG0, tIG1 = aI1 * aG1;
        float num0 = fmaf(c0, tIG0, (1.0f - eg0) * aF0);
        float num1 = fmaf(c1, tIG1, (1.0f - eg1) * aF1);
        float D0 = aF0 * tIG0, D1 = aF1 * tIG1;
        float rD = __builtin_amdgcn_rcpf(D0 * D1);        // paired rcp #1
        c0 = num0 * (rD * D1);
        c1 = num1 * (rD * D0);
        float ec0 = __builtin_amdgcn_exp2f(c0 * (-2.0f * L2E));
        float ec1 = __builtin_amdgcn_exp2f(c1 * (-2.0f * L2E));
        float H0 = aO0 * (1.0f + ec0), H1 = aO1 * (1.0f + ec1);
        float rH = __builtin_amdgcn_rcpf(H0 * H1);        // paired rcp #2
        h0 = (1.0f - ec0) * (rH * H1);
        h1 = (1.0f - ec1) * (rH * H0);

        // adjacent hiddens -> one b32 write of the packed pair
        buf[wr] = __builtin_bit_cast(unsigned int, __builtin_amdgcn_cvt_pkrtz(h0, h1));

        __builtin_amdgcn_s_setprio(0);

        // next step's C-init in the pre-barrier slack
        #pragma unroll
        for (int tau = 0; tau < 2; ++tau)
            #pragma unroll
            for (int r = 0; r < 4; ++r)
                cq[tau][r] = fmaf(xt1, wih[tau][r], bia[tau][r]);

        __syncthreads();
        // B-frag: pairs quad*4..+3 of batch col = k quad*8..quad*8+7
        uint4 bv = *(const uint4*)&buf[col * 20 + quad * 4];
        bfrag = __builtin_bit_cast(f16x8, bv);
    }

    // ---- epilogue: out[b] = sum_j h_j * W_lin[j] + b_lin ----
    float v = fmaf(h0, wl0, h1 * wl1);
    v += __shfl_xor(v, 16);            // combine quads
    v += __shfl_xor(v, 32);
    if (lane < 16) ps[wv * 16 + col] = v;
    __syncthreads();
    if (tid < 16)
        out[base + tid] = b_lin[0] + ps[tid] + ps[16 + tid] + ps[32 + tid] + ps[48 + tid];
}

extern "C" void kernel_launch(void* const* d_in, const int* in_sizes, int n_in,
                              void* d_out, int out_size, void* d_ws, size_t ws_size,
                              hipStream_t stream) {
    const float* x     = (const float*)d_in[0];
    const float* W_ih  = (const float*)d_in[1];
    const float* W_hh  = (const float*)d_in[2];
    const float* b_ih  = (const float*)d_in[3];
    const float* b_hh  = (const float*)d_in[4];
    const float* W_lin = (const float*)d_in[5];
    const float* b_lin = (const float*)d_in[6];
    float* out = (float*)d_out;

    const int B = in_sizes[0] / 512;   // 8192
    dim3 grid(B / 16), block(256);
    lstm_ct4r<<<grid, block, 0, stream>>>(x, W_ih, W_hh, b_ih, b_hh, W_lin, b_lin, out);
}